// Round 25
// baseline (346.557 us; speedup 1.0000x reference)
//
#include <hip/hip_runtime.h>
#include <cstdint>
#include <cstddef>

typedef __attribute__((ext_vector_type(8))) short bf16x8;
typedef __attribute__((ext_vector_type(4))) float f32x4;
typedef __attribute__((ext_vector_type(4))) unsigned short us4;
typedef __attribute__((ext_vector_type(8))) unsigned short us8;

#define NHEADS 12
#define BATCH 8
#define SEQ 1024
#define HDIM 64
#define CDIM 768
#define QKV_N 2304
#define BHND ((size_t)(BATCH) * NHEADS * SEQ * HDIM)   // 6291456
#define NX   ((size_t)8192 * 768)                      // 6291456

__device__ __forceinline__ unsigned short f2bf(float f) {
    union { float f; uint32_t u; } v; v.f = f;
    uint32_t u = v.u;
    u += 0x7fffu + ((u >> 16) & 1u);   // RNE
    return (unsigned short)(u >> 16);
}

// ---------------------------------------------------------------------------
// GEMM1: qkv = x[8192,768](fp32) @ W_qkv[768,2304](fp32), bf16 MFMA compute,
// scatter to Q|K|V [B][H][N][D] bf16 ws. Q pre-scaled by 1/8 (exact pow2).
// ---------------------------------------------------------------------------
__global__ __launch_bounds__(256) void qkv_gemm(const float* __restrict__ x,
                                                const float* __restrict__ w,
                                                unsigned short* __restrict__ qkv) {
    __shared__ unsigned short a_lds[128][40];
    __shared__ unsigned short b_lds[128][40];
    const int m0 = blockIdx.y * 128;
    const int n0 = blockIdx.x * 128;
    const int t = threadIdx.x;
    const int lane = t & 63;
    const int wv = t >> 6;
    const int wm = wv >> 1, wn = wv & 1;
    const int lr = lane & 15, kg = lane >> 4;

    f32x4 acc[4][4];
#pragma unroll
    for (int i = 0; i < 4; ++i)
#pragma unroll
        for (int j = 0; j < 4; ++j) acc[i][j] = (f32x4)0.f;

    const int ar = t >> 3, ac4 = t & 7;
    const int bk = t >> 5, bc4 = t & 31;

    for (int kt = 0; kt < 24; ++kt) {
        const int k0 = kt * 32;
        __syncthreads();
#pragma unroll
        for (int i = 0; i < 4; ++i) {
            const int r = ar + 32 * i;
            f32x4 av = *(const f32x4*)&x[(size_t)(m0 + r) * CDIM + k0 + ac4 * 4];
            us4 o;
#pragma unroll
            for (int j = 0; j < 4; ++j) o[j] = f2bf(av[j]);
            *(us4*)&a_lds[r][ac4 * 4] = o;
        }
#pragma unroll
        for (int i = 0; i < 4; ++i) {
            const int k = bk + 8 * i;
            f32x4 wv4 = *(const f32x4*)&w[(size_t)(k0 + k) * QKV_N + n0 + bc4 * 4];
#pragma unroll
            for (int j = 0; j < 4; ++j) b_lds[bc4 * 4 + j][k] = f2bf(wv4[j]);
        }
        __syncthreads();

        bf16x8 afr[4], bfr[4];
#pragma unroll
        for (int i = 0; i < 4; ++i)
            afr[i] = *(const bf16x8*)&a_lds[wm * 64 + i * 16 + lr][kg * 8];
#pragma unroll
        for (int j = 0; j < 4; ++j)
            bfr[j] = *(const bf16x8*)&b_lds[wn * 64 + j * 16 + lr][kg * 8];
#pragma unroll
        for (int i = 0; i < 4; ++i)
#pragma unroll
            for (int j = 0; j < 4; ++j)
                acc[i][j] = __builtin_amdgcn_mfma_f32_16x16x32_bf16(afr[i], bfr[j],
                                                                    acc[i][j], 0, 0, 0);
    }

#pragma unroll
    for (int j = 0; j < 4; ++j) {
        const int c = n0 + wn * 64 + j * 16 + lr;
        const int three = (c >= 1536) ? 2 : ((c >= 768) ? 1 : 0);
        const int rem = c - three * 768;
        const int h = rem >> 6, d = rem & 63;
        const float mul = (three == 0) ? 0.125f : 1.0f;
#pragma unroll
        for (int i = 0; i < 4; ++i) {
#pragma unroll
            for (int rg = 0; rg < 4; ++rg) {
                const int m = m0 + wm * 64 + i * 16 + kg * 4 + rg;
                const int bb = m >> 10, n = m & 1023;
                qkv[(size_t)three * BHND +
                    ((size_t)(bb * NHEADS + h) * SEQ + n) * HDIM + d] =
                    f2bf(acc[i][j][rg] * mul);
            }
        }
    }
}

// ---------------------------------------------------------------------------
// Flash attention: per (bh, q-tile of 64). 4 waves x 16 q-rows. KV tiles of 64.
// ---------------------------------------------------------------------------
__global__ __launch_bounds__(256) void attn_kernel(const unsigned short* __restrict__ qkv,
                                                   unsigned short* __restrict__ aout) {
    __shared__ unsigned short k_lds[64][72];
    __shared__ unsigned short v_lds[64][72];
    __shared__ unsigned short p_lds[4][16][72];
    const int bh = blockIdx.y;
    const int qt = blockIdx.x;
    const int t = threadIdx.x, lane = t & 63, w = t >> 6;
    const int lr = lane & 15, kg = lane >> 4;
    const unsigned short* Q = qkv + (size_t)bh * SEQ * HDIM;
    const unsigned short* K = qkv + BHND + (size_t)bh * SEQ * HDIM;
    const unsigned short* V = qkv + 2 * BHND + (size_t)bh * SEQ * HDIM;

    const int q0 = qt * 64 + w * 16;
    bf16x8 qf[2];
#pragma unroll
    for (int ks = 0; ks < 2; ++ks)
        qf[ks] = *(const bf16x8*)&Q[(size_t)(q0 + lr) * HDIM + ks * 32 + kg * 8];

    float mval[4], lsum[4];
    f32x4 oacc[4];
#pragma unroll
    for (int r = 0; r < 4; ++r) { mval[r] = -1e30f; lsum[r] = 0.f; }
#pragma unroll
    for (int jd = 0; jd < 4; ++jd) oacc[jd] = (f32x4)0.f;

    for (int kv = 0; kv < 16; ++kv) {
        const int kb = kv * 64;
        __syncthreads();
#pragma unroll
        for (int i = 0; i < 2; ++i) {
            const int c = t + 256 * i;
            const int key = c >> 3, seg = c & 7;
            *(us8*)&k_lds[key][seg * 8] =
                *(const us8*)&K[(size_t)(kb + key) * HDIM + seg * 8];
        }
#pragma unroll
        for (int i = 0; i < 4; ++i) {
            const int c = t + 256 * i;
            const int key = c >> 4, d4 = c & 15;
            us4 vvv = *(const us4*)&V[(size_t)(kb + key) * HDIM + d4 * 4];
#pragma unroll
            for (int j = 0; j < 4; ++j) v_lds[d4 * 4 + j][key] = vvv[j];
        }
        __syncthreads();

        f32x4 s[4];
#pragma unroll
        for (int j = 0; j < 4; ++j) {
            s[j] = (f32x4)0.f;
#pragma unroll
            for (int ks = 0; ks < 2; ++ks) {
                bf16x8 kf = *(const bf16x8*)&k_lds[j * 16 + lr][ks * 32 + kg * 8];
                s[j] = __builtin_amdgcn_mfma_f32_16x16x32_bf16(qf[ks], kf, s[j], 0, 0, 0);
            }
        }

        float p[4][4];
#pragma unroll
        for (int r = 0; r < 4; ++r) {
            float mx = fmaxf(fmaxf(s[0][r], s[1][r]), fmaxf(s[2][r], s[3][r]));
#pragma unroll
            for (int mm = 1; mm < 16; mm <<= 1) mx = fmaxf(mx, __shfl_xor(mx, mm, 64));
            const float mnew = fmaxf(mval[r], mx);
            const float corr = __expf(mval[r] - mnew);
            float rs = 0.f;
#pragma unroll
            for (int j = 0; j < 4; ++j) { p[j][r] = __expf(s[j][r] - mnew); rs += p[j][r]; }
#pragma unroll
            for (int mm = 1; mm < 16; mm <<= 1) rs += __shfl_xor(rs, mm, 64);
            lsum[r] = lsum[r] * corr + rs;
            mval[r] = mnew;
#pragma unroll
            for (int jd = 0; jd < 4; ++jd) oacc[jd][r] *= corr;
        }

#pragma unroll
        for (int j = 0; j < 4; ++j)
#pragma unroll
            for (int r = 0; r < 4; ++r)
                p_lds[w][kg * 4 + r][j * 16 + lr] = f2bf(p[j][r]);

        __syncthreads();

#pragma unroll
        for (int ks = 0; ks < 2; ++ks) {
            bf16x8 pf = *(const bf16x8*)&p_lds[w][lr][ks * 32 + kg * 8];
#pragma unroll
            for (int jd = 0; jd < 4; ++jd) {
                bf16x8 vf = *(const bf16x8*)&v_lds[jd * 16 + lr][ks * 32 + kg * 8];
                oacc[jd] = __builtin_amdgcn_mfma_f32_16x16x32_bf16(pf, vf, oacc[jd], 0, 0, 0);
            }
        }
    }

    const int bb = bh / NHEADS, h = bh % NHEADS;
#pragma unroll
    for (int jd = 0; jd < 4; ++jd) {
#pragma unroll
        for (int r = 0; r < 4; ++r) {
            const int n = q0 + kg * 4 + r;
            const int d = jd * 16 + lr;
            aout[((size_t)(bb * SEQ + n)) * CDIM + h * HDIM + d] =
                f2bf(oacc[jd][r] / lsum[r]);
        }
    }
}

// ---------------------------------------------------------------------------
// GEMM2: out = attn_out[8192,768](bf16) @ W_proj[768,768](fp32) -> FP32 out
// (the one change vs round 5: d_out is FP32 — proven by R21-R24 probes)
// ---------------------------------------------------------------------------
__global__ __launch_bounds__(256) void proj_gemm(const unsigned short* __restrict__ a,
                                                 const float* __restrict__ w,
                                                 float* __restrict__ out) {
    __shared__ unsigned short a_lds[128][40];
    __shared__ unsigned short b_lds[128][40];
    const int m0 = blockIdx.y * 128;
    const int n0 = blockIdx.x * 128;
    const int t = threadIdx.x;
    const int lane = t & 63;
    const int wv = t >> 6;
    const int wm = wv >> 1, wn = wv & 1;
    const int lr = lane & 15, kg = lane >> 4;

    f32x4 acc[4][4];
#pragma unroll
    for (int i = 0; i < 4; ++i)
#pragma unroll
        for (int j = 0; j < 4; ++j) acc[i][j] = (f32x4)0.f;

    const int ar = t >> 3, ac4 = t & 7;
    const int bk = t >> 5, bc4 = t & 31;

    for (int kt = 0; kt < 24; ++kt) {
        const int k0 = kt * 32;
        __syncthreads();
#pragma unroll
        for (int i = 0; i < 4; ++i) {
            const int r = ar + 32 * i;
            *(us4*)&a_lds[r][ac4 * 4] =
                *(const us4*)&a[(size_t)(m0 + r) * CDIM + k0 + ac4 * 4];
        }
#pragma unroll
        for (int i = 0; i < 4; ++i) {
            const int k = bk + 8 * i;
            f32x4 wv4 = *(const f32x4*)&w[(size_t)(k0 + k) * CDIM + n0 + bc4 * 4];
#pragma unroll
            for (int j = 0; j < 4; ++j) b_lds[bc4 * 4 + j][k] = f2bf(wv4[j]);
        }
        __syncthreads();

        bf16x8 afr[4], bfr[4];
#pragma unroll
        for (int i = 0; i < 4; ++i)
            afr[i] = *(const bf16x8*)&a_lds[wm * 64 + i * 16 + lr][kg * 8];
#pragma unroll
        for (int j = 0; j < 4; ++j)
            bfr[j] = *(const bf16x8*)&b_lds[wn * 64 + j * 16 + lr][kg * 8];
#pragma unroll
        for (int i = 0; i < 4; ++i)
#pragma unroll
            for (int j = 0; j < 4; ++j)
                acc[i][j] = __builtin_amdgcn_mfma_f32_16x16x32_bf16(afr[i], bfr[j],
                                                                    acc[i][j], 0, 0, 0);
    }

#pragma unroll
    for (int i = 0; i < 4; ++i)
#pragma unroll
        for (int j = 0; j < 4; ++j)
#pragma unroll
            for (int rg = 0; rg < 4; ++rg) {
                const int m = m0 + wm * 64 + i * 16 + kg * 4 + rg;
                const int c = n0 + wn * 64 + j * 16 + lr;
                out[(size_t)m * CDIM + c] = acc[i][j][rg];   // FP32 store
            }
}

// ---------------------------------------------------------------------------
extern "C" void kernel_launch(void* const* d_in, const int* in_sizes, int n_in,
                              void* d_out, int out_size, void* d_ws, size_t ws_size,
                              hipStream_t stream) {
    const float* x      = (const float*)d_in[0];
    const float* w_qkv  = (const float*)d_in[1];
    const float* w_proj = (const float*)d_in[2];

    // ws layout (u16 elems): qkv 3*BHND (37.75 MB) | aout NX (12.6 MB)
    unsigned short* qkv  = (unsigned short*)d_ws;
    unsigned short* aout = qkv + 3 * BHND;
    float* out = (float*)d_out;

    qkv_gemm<<<dim3(18, 64), 256, 0, stream>>>(x, w_qkv, qkv);
    attn_kernel<<<dim3(16, 96), 256, 0, stream>>>(qkv, aout);
    proj_gemm<<<dim3(6, 64), 256, 0, stream>>>(aout, w_proj, out);
}

// Round 26
// 210.252 us; speedup vs baseline: 1.6483x; 1.6483x over previous
//
#include <hip/hip_runtime.h>
#include <cstdint>
#include <cstddef>

typedef __attribute__((ext_vector_type(8))) short bf16x8;
typedef __attribute__((ext_vector_type(4))) float f32x4;
typedef __attribute__((ext_vector_type(4))) unsigned short us4;
typedef __attribute__((ext_vector_type(8))) unsigned short us8;

#define NHEADS 12
#define BATCH 8
#define SEQ 1024
#define HDIM 64
#define CDIM 768
#define QKV_N 2304
#define BHND ((size_t)(BATCH) * NHEADS * SEQ * HDIM)   // 6291456
#define NX   ((size_t)8192 * 768)                      // 6291456
#define NWQ  ((size_t)768 * 2304)                      // 1769472
#define NWP  ((size_t)768 * 768)                       // 589824

__device__ __forceinline__ unsigned short f2bf(float f) {
    union { float f; uint32_t u; } v; v.f = f;
    uint32_t u = v.u;
    u += 0x7fffu + ((u >> 16) & 1u);   // RNE
    return (unsigned short)(u >> 16);
}

// async global->LDS, 16B per lane; LDS dest = wave-uniform base + lane*16
__device__ __forceinline__ void gl_lds16(const unsigned short* g, unsigned short* l) {
    __builtin_amdgcn_global_load_lds(
        (const __attribute__((address_space(1))) void*)g,
        (__attribute__((address_space(3))) void*)l, 16, 0, 0);
}

// ---------------------------------------------------------------------------
// x fp32 -> bf16 (grid-stride, vectorized)
// ---------------------------------------------------------------------------
__global__ __launch_bounds__(256) void conv_x(const float* __restrict__ in,
                                              unsigned short* __restrict__ out) {
    const size_t stride = (size_t)gridDim.x * blockDim.x;
    for (size_t i8 = (size_t)blockIdx.x * 256 + threadIdx.x; i8 < NX / 8; i8 += stride) {
        f32x4 a = *(const f32x4*)&in[i8 * 8];
        f32x4 b = *(const f32x4*)&in[i8 * 8 + 4];
        us8 o;
#pragma unroll
        for (int j = 0; j < 4; ++j) { o[j] = f2bf(a[j]); o[4 + j] = f2bf(b[j]); }
        *(us8*)&out[i8 * 8] = o;
    }
}

// ---------------------------------------------------------------------------
// Transpose-convert: in [R][C] fp32 -> out [C][R] bf16 (64x64 LDS tiles)
// ---------------------------------------------------------------------------
__global__ __launch_bounds__(256) void tconv(const float* __restrict__ in,
                                             unsigned short* __restrict__ out,
                                             int R, int C) {
    __shared__ unsigned short tile[64][68];
    const int bx = blockIdx.x * 64;   // input col base
    const int by = blockIdx.y * 64;   // input row base
    const int t = threadIdx.x;
    const int rr = t >> 4;            // 0..15
    const int c4 = (t & 15) * 4;
#pragma unroll
    for (int i = 0; i < 4; ++i) {
        const int r = rr + i * 16;
        f32x4 v = *(const f32x4*)&in[(size_t)(by + r) * C + bx + c4];
#pragma unroll
        for (int j = 0; j < 4; ++j) tile[c4 + j][r] = f2bf(v[j]);
    }
    __syncthreads();
#pragma unroll
    for (int i = 0; i < 4; ++i) {
        const int r = rr + i * 16;    // output row = input col
        us4 o;
#pragma unroll
        for (int j = 0; j < 4; ++j) o[j] = tile[r][c4 + j];
        *(us4*)&out[(size_t)(bx + r) * R + by + c4] = o;
    }
}

// ---------------------------------------------------------------------------
// GEMM1 (m97 structure): A=xb[8192][768]bf16, BT=wqt[2304][768]bf16.
// 128x128 tile, BK=32, global_load_lds(16B) staging, linear LDS, 16 MFMA/step.
// Epilogue: scatter Q|K|V [B][H][N][D] bf16, Q *= 1/8.
// ---------------------------------------------------------------------------
__global__ __launch_bounds__(256) void qkv_gemm2(const unsigned short* __restrict__ A,
                                                 const unsigned short* __restrict__ BT,
                                                 unsigned short* __restrict__ qkv) {
    __shared__ unsigned short a_lds[128][32];
    __shared__ unsigned short b_lds[128][32];
    const int m0 = blockIdx.y * 128;
    const int n0 = blockIdx.x * 128;
    const int t = threadIdx.x, lane = t & 63, w = t >> 6;
    const int wm = w >> 1, wn = w & 1;
    const int lr = lane & 15, kg = lane >> 4;
    const int srow = w * 16 + (lane >> 2);   // staging row within 64-row chunk
    const int scol = (lane & 3) * 8;         // staging col (bf16 elems)

    f32x4 acc[4][4];
#pragma unroll
    for (int i = 0; i < 4; ++i)
#pragma unroll
        for (int j = 0; j < 4; ++j) acc[i][j] = (f32x4)0.f;

    unsigned short* ab0 = &a_lds[0][0] + w * 512;         // rows w*16..+15
    unsigned short* ab1 = &a_lds[0][0] + (4 + w) * 512;   // rows 64+w*16..
    unsigned short* bb0 = &b_lds[0][0] + w * 512;
    unsigned short* bb1 = &b_lds[0][0] + (4 + w) * 512;

    for (int kt = 0; kt < 24; ++kt) {
        const int k0 = kt * 32;
        __syncthreads();   // all waves done reading previous tile
        gl_lds16(&A[(size_t)(m0 + srow) * CDIM + k0 + scol], ab0);
        gl_lds16(&A[(size_t)(m0 + 64 + srow) * CDIM + k0 + scol], ab1);
        gl_lds16(&BT[(size_t)(n0 + srow) * CDIM + k0 + scol], bb0);
        gl_lds16(&BT[(size_t)(n0 + 64 + srow) * CDIM + k0 + scol], bb1);
        __syncthreads();   // compiler drains vmcnt(0) before barrier

        bf16x8 afr[4], bfr[4];
#pragma unroll
        for (int i = 0; i < 4; ++i)
            afr[i] = *(const bf16x8*)&a_lds[wm * 64 + i * 16 + lr][kg * 8];
#pragma unroll
        for (int j = 0; j < 4; ++j)
            bfr[j] = *(const bf16x8*)&b_lds[wn * 64 + j * 16 + lr][kg * 8];
#pragma unroll
        for (int i = 0; i < 4; ++i)
#pragma unroll
            for (int j = 0; j < 4; ++j)
                acc[i][j] = __builtin_amdgcn_mfma_f32_16x16x32_bf16(afr[i], bfr[j],
                                                                    acc[i][j], 0, 0, 0);
    }

#pragma unroll
    for (int j = 0; j < 4; ++j) {
        const int c = n0 + wn * 64 + j * 16 + lr;
        const int three = (c >= 1536) ? 2 : ((c >= 768) ? 1 : 0);
        const int rem = c - three * 768;
        const int h = rem >> 6, d = rem & 63;
        const float mul = (three == 0) ? 0.125f : 1.0f;
#pragma unroll
        for (int i = 0; i < 4; ++i) {
#pragma unroll
            for (int rg = 0; rg < 4; ++rg) {
                const int m = m0 + wm * 64 + i * 16 + kg * 4 + rg;
                const int bb = m >> 10, n = m & 1023;
                qkv[(size_t)three * BHND +
                    ((size_t)(bb * NHEADS + h) * SEQ + n) * HDIM + d] =
                    f2bf(acc[i][j][rg] * mul);
            }
        }
    }
}

// ---------------------------------------------------------------------------
// Flash attention (unchanged from passing round 25)
// ---------------------------------------------------------------------------
__global__ __launch_bounds__(256) void attn_kernel(const unsigned short* __restrict__ qkv,
                                                   unsigned short* __restrict__ aout) {
    __shared__ unsigned short k_lds[64][72];
    __shared__ unsigned short v_lds[64][72];
    __shared__ unsigned short p_lds[4][16][72];
    const int bh = blockIdx.y;
    const int qt = blockIdx.x;
    const int t = threadIdx.x, lane = t & 63, w = t >> 6;
    const int lr = lane & 15, kg = lane >> 4;
    const unsigned short* Q = qkv + (size_t)bh * SEQ * HDIM;
    const unsigned short* K = qkv + BHND + (size_t)bh * SEQ * HDIM;
    const unsigned short* V = qkv + 2 * BHND + (size_t)bh * SEQ * HDIM;

    const int q0 = qt * 64 + w * 16;
    bf16x8 qf[2];
#pragma unroll
    for (int ks = 0; ks < 2; ++ks)
        qf[ks] = *(const bf16x8*)&Q[(size_t)(q0 + lr) * HDIM + ks * 32 + kg * 8];

    float mval[4], lsum[4];
    f32x4 oacc[4];
#pragma unroll
    for (int r = 0; r < 4; ++r) { mval[r] = -1e30f; lsum[r] = 0.f; }
#pragma unroll
    for (int jd = 0; jd < 4; ++jd) oacc[jd] = (f32x4)0.f;

    for (int kv = 0; kv < 16; ++kv) {
        const int kb = kv * 64;
        __syncthreads();
#pragma unroll
        for (int i = 0; i < 2; ++i) {
            const int c = t + 256 * i;
            const int key = c >> 3, seg = c & 7;
            *(us8*)&k_lds[key][seg * 8] =
                *(const us8*)&K[(size_t)(kb + key) * HDIM + seg * 8];
        }
#pragma unroll
        for (int i = 0; i < 4; ++i) {
            const int c = t + 256 * i;
            const int key = c >> 4, d4 = c & 15;
            us4 vvv = *(const us4*)&V[(size_t)(kb + key) * HDIM + d4 * 4];
#pragma unroll
            for (int j = 0; j < 4; ++j) v_lds[d4 * 4 + j][key] = vvv[j];
        }
        __syncthreads();

        f32x4 s[4];
#pragma unroll
        for (int j = 0; j < 4; ++j) {
            s[j] = (f32x4)0.f;
#pragma unroll
            for (int ks = 0; ks < 2; ++ks) {
                bf16x8 kf = *(const bf16x8*)&k_lds[j * 16 + lr][ks * 32 + kg * 8];
                s[j] = __builtin_amdgcn_mfma_f32_16x16x32_bf16(qf[ks], kf, s[j], 0, 0, 0);
            }
        }

        float p[4][4];
#pragma unroll
        for (int r = 0; r < 4; ++r) {
            float mx = fmaxf(fmaxf(s[0][r], s[1][r]), fmaxf(s[2][r], s[3][r]));
#pragma unroll
            for (int mm = 1; mm < 16; mm <<= 1) mx = fmaxf(mx, __shfl_xor(mx, mm, 64));
            const float mnew = fmaxf(mval[r], mx);
            const float corr = __expf(mval[r] - mnew);
            float rs = 0.f;
#pragma unroll
            for (int j = 0; j < 4; ++j) { p[j][r] = __expf(s[j][r] - mnew); rs += p[j][r]; }
#pragma unroll
            for (int mm = 1; mm < 16; mm <<= 1) rs += __shfl_xor(rs, mm, 64);
            lsum[r] = lsum[r] * corr + rs;
            mval[r] = mnew;
#pragma unroll
            for (int jd = 0; jd < 4; ++jd) oacc[jd][r] *= corr;
        }

#pragma unroll
        for (int j = 0; j < 4; ++j)
#pragma unroll
            for (int r = 0; r < 4; ++r)
                p_lds[w][kg * 4 + r][j * 16 + lr] = f2bf(p[j][r]);

        __syncthreads();

#pragma unroll
        for (int ks = 0; ks < 2; ++ks) {
            bf16x8 pf = *(const bf16x8*)&p_lds[w][lr][ks * 32 + kg * 8];
#pragma unroll
            for (int jd = 0; jd < 4; ++jd) {
                bf16x8 vf = *(const bf16x8*)&v_lds[jd * 16 + lr][ks * 32 + kg * 8];
                oacc[jd] = __builtin_amdgcn_mfma_f32_16x16x32_bf16(pf, vf, oacc[jd], 0, 0, 0);
            }
        }
    }

    const int bb = bh / NHEADS, h = bh % NHEADS;
#pragma unroll
    for (int jd = 0; jd < 4; ++jd) {
#pragma unroll
        for (int r = 0; r < 4; ++r) {
            const int n = q0 + kg * 4 + r;
            const int d = jd * 16 + lr;
            aout[((size_t)(bb * SEQ + n)) * CDIM + h * HDIM + d] =
                f2bf(oacc[jd][r] / lsum[r]);
        }
    }
}

// ---------------------------------------------------------------------------
// GEMM2 (m97 structure): A=aout[8192][768]bf16, BT=wpt[768][768]bf16 -> fp32 out
// ---------------------------------------------------------------------------
__global__ __launch_bounds__(256) void proj_gemm2(const unsigned short* __restrict__ A,
                                                  const unsigned short* __restrict__ BT,
                                                  float* __restrict__ out) {
    __shared__ unsigned short a_lds[128][32];
    __shared__ unsigned short b_lds[128][32];
    const int m0 = blockIdx.y * 128;
    const int n0 = blockIdx.x * 128;
    const int t = threadIdx.x, lane = t & 63, w = t >> 6;
    const int wm = w >> 1, wn = w & 1;
    const int lr = lane & 15, kg = lane >> 4;
    const int srow = w * 16 + (lane >> 2);
    const int scol = (lane & 3) * 8;

    f32x4 acc[4][4];
#pragma unroll
    for (int i = 0; i < 4; ++i)
#pragma unroll
        for (int j = 0; j < 4; ++j) acc[i][j] = (f32x4)0.f;

    unsigned short* ab0 = &a_lds[0][0] + w * 512;
    unsigned short* ab1 = &a_lds[0][0] + (4 + w) * 512;
    unsigned short* bb0 = &b_lds[0][0] + w * 512;
    unsigned short* bb1 = &b_lds[0][0] + (4 + w) * 512;

    for (int kt = 0; kt < 24; ++kt) {
        const int k0 = kt * 32;
        __syncthreads();
        gl_lds16(&A[(size_t)(m0 + srow) * CDIM + k0 + scol], ab0);
        gl_lds16(&A[(size_t)(m0 + 64 + srow) * CDIM + k0 + scol], ab1);
        gl_lds16(&BT[(size_t)(n0 + srow) * CDIM + k0 + scol], bb0);
        gl_lds16(&BT[(size_t)(n0 + 64 + srow) * CDIM + k0 + scol], bb1);
        __syncthreads();

        bf16x8 afr[4], bfr[4];
#pragma unroll
        for (int i = 0; i < 4; ++i)
            afr[i] = *(const bf16x8*)&a_lds[wm * 64 + i * 16 + lr][kg * 8];
#pragma unroll
        for (int j = 0; j < 4; ++j)
            bfr[j] = *(const bf16x8*)&b_lds[wn * 64 + j * 16 + lr][kg * 8];
#pragma unroll
        for (int i = 0; i < 4; ++i)
#pragma unroll
            for (int j = 0; j < 4; ++j)
                acc[i][j] = __builtin_amdgcn_mfma_f32_16x16x32_bf16(afr[i], bfr[j],
                                                                    acc[i][j], 0, 0, 0);
    }

#pragma unroll
    for (int i = 0; i < 4; ++i)
#pragma unroll
        for (int j = 0; j < 4; ++j)
#pragma unroll
            for (int rg = 0; rg < 4; ++rg) {
                const int m = m0 + wm * 64 + i * 16 + kg * 4 + rg;
                const int c = n0 + wn * 64 + j * 16 + lr;
                out[(size_t)m * CDIM + c] = acc[i][j][rg];
            }
}

// ---------------------------------------------------------------------------
extern "C" void kernel_launch(void* const* d_in, const int* in_sizes, int n_in,
                              void* d_out, int out_size, void* d_ws, size_t ws_size,
                              hipStream_t stream) {
    const float* x      = (const float*)d_in[0];
    const float* w_qkv  = (const float*)d_in[1];
    const float* w_proj = (const float*)d_in[2];

    // ws (u16): qkv 3*BHND | aout NX | xb NX | wqt NWQ | wpt NWP  = 64.5 MiB
    unsigned short* qkv  = (unsigned short*)d_ws;
    unsigned short* aout = qkv + 3 * BHND;
    unsigned short* xb   = aout + NX;
    unsigned short* wqt  = xb + NX;
    unsigned short* wpt  = wqt + NWQ;
    float* out = (float*)d_out;

    conv_x<<<2048, 256, 0, stream>>>(x, xb);
    tconv<<<dim3(QKV_N / 64, CDIM / 64), 256, 0, stream>>>(w_qkv, wqt, CDIM, QKV_N);
    tconv<<<dim3(CDIM / 64, CDIM / 64), 256, 0, stream>>>(w_proj, wpt, CDIM, CDIM);
    qkv_gemm2<<<dim3(18, 64), 256, 0, stream>>>(xb, wqt, qkv);
    attn_kernel<<<dim3(16, 96), 256, 0, stream>>>(qkv, aout);
    proj_gemm2<<<dim3(6, 64), 256, 0, stream>>>(aout, wpt, out);
}